// Round 2
// baseline (343.880 us; speedup 1.0000x reference)
//
#include <hip/hip_runtime.h>

typedef __attribute__((ext_vector_type(8))) short     bf16x8;
typedef __attribute__((ext_vector_type(4))) float     f32x4;
typedef __attribute__((ext_vector_type(2))) float     f32x2;
typedef __attribute__((ext_vector_type(4))) unsigned short u16x4;

#define NB 4096          // batch
#define NU 1024          // units
#define OUT_STRIDE 1086  // o(1024) + pi(20) + mux(20) + muy(20) + xp + yp
#define NS_STRIDE 1026
#define NS_BASE (4096*1086)

__device__ __forceinline__ unsigned short f2bf(float x) {
  unsigned int u = __float_as_uint(x);
  unsigned int r = (u + 0x7FFFu + ((u >> 16) & 1u)) >> 16;
  return (unsigned short)r;
}
__device__ __forceinline__ float sigmoidf(float x) { return 1.f / (1.f + expf(-x)); }

__device__ __forceinline__ void gld_lds16(const void* g, void* l) {
  __builtin_amdgcn_global_load_lds((const __attribute__((address_space(1))) void*)g,
                                   (__attribute__((address_space(3))) void*)l, 16, 0, 0);
}

// ---------- transpose-convert R (1024 x 4096 f32) -> RbT (4096 x 1024 bf16) ----------
__global__ __launch_bounds__(256)
void transposeR(const float* __restrict__ R, unsigned short* __restrict__ Bt) {
  __shared__ float t[64][65];
  const int tx = threadIdx.x & 63, ty = threadIdx.x >> 6;  // ty 0..3
  const int j0 = blockIdx.x * 64, k0 = blockIdx.y * 64;
#pragma unroll
  for (int i = 0; i < 64; i += 4)
    t[ty + i][tx] = R[(size_t)(k0 + ty + i) * 4096 + j0 + tx];
  __syncthreads();
#pragma unroll
  for (int i = 0; i < 64; i += 4) {
    const int j = ty + i;
    Bt[(size_t)(j0 + j) * 1024 + k0 + tx] = f2bf(t[tx][j]);
  }
}

// ---------- convert h_tm1 (states[:, :1024]) -> bf16 ----------
__global__ __launch_bounds__(256)
void convertH(const float* __restrict__ states, unsigned short* __restrict__ hb) {
  const int idx = blockIdx.x * 256 + threadIdx.x;  // 1M threads
  const int b = idx >> 8, u = (idx & 255) * 4;
  const float* sp = states + (size_t)b * 1026 + u;
  f32x2 v0 = *(const f32x2*)sp, v1 = *(const f32x2*)(sp + 2);
  u16x4 w;
  w[0] = f2bf(v0[0]); w[1] = f2bf(v0[1]); w[2] = f2bf(v1[0]); w[3] = f2bf(v1[1]);
  *(u16x4*)&hb[(size_t)b * 1024 + u] = w;
}

// ---------- MFMA GEMM: C[M=4096, N] = A[4096,1024] * Bt[N,1024]^T ----------
// EPI 0: plain f32 store (zr).  EPI 2: hh->h epilogue.  EPI 3: o epilogue.
template<int EPI>
__global__ __launch_bounds__(256)
void gemm_k(const unsigned short* __restrict__ A,
            const unsigned short* __restrict__ Bt,
            float* __restrict__ C, int ldc,
            const int* __restrict__ chv,
            const float* __restrict__ states,
            const float* __restrict__ kc, int colbase,
            const float* __restrict__ kd,
            const float* __restrict__ bias, int biasoff,
            const float* __restrict__ zbuf,
            float* __restrict__ out2,
            unsigned short* __restrict__ hb2) {
  __shared__ unsigned short Al[128 * 32];
  __shared__ unsigned short Bl[128 * 32];
  __shared__ int   chs[128];
  __shared__ float d0s[128], d1s[128];

  const int tid = threadIdx.x;
  const int lane = tid & 63;
  const int wave = tid >> 6;
  const int wr = wave >> 1, wc = wave & 1;
  const int m0 = blockIdx.y * 128;
  const int n0 = blockIdx.x * 128;

  if (EPI != 0 && tid < 128) {
    const int r = m0 + tid;
    chs[tid] = chv[r];
    d0s[tid] = states[(size_t)r * 1026 + 1024];
    d1s[tid] = states[(size_t)r * 1026 + 1025];
  }

  f32x4 acc[4][4] = {};

  const int c0 = tid, c1 = tid + 256;
  const int ar0 = c0 >> 2, ak0 = (c0 & 3) * 8;
  const int ar1 = c1 >> 2, ak1 = (c1 & 3) * 8;
  const unsigned short* Ag = A + (size_t)m0 * 1024;
  const unsigned short* Bg = Bt + (size_t)n0 * 1024;

  for (int k0 = 0; k0 < 1024; k0 += 32) {
    __syncthreads();
    gld_lds16(Ag + (size_t)ar0 * 1024 + k0 + ak0, &Al[c0 * 8]);
    gld_lds16(Ag + (size_t)ar1 * 1024 + k0 + ak1, &Al[c1 * 8]);
    gld_lds16(Bg + (size_t)ar0 * 1024 + k0 + ak0, &Bl[c0 * 8]);
    gld_lds16(Bg + (size_t)ar1 * 1024 + k0 + ak1, &Bl[c1 * 8]);
    __syncthreads();
    bf16x8 af[4], bfr[4];
    const int arow = lane & 15, kg = (lane >> 4) * 8;
#pragma unroll
    for (int mi = 0; mi < 4; ++mi)
      af[mi] = *(const bf16x8*)&Al[(wr * 64 + mi * 16 + arow) * 32 + kg];
#pragma unroll
    for (int ni = 0; ni < 4; ++ni)
      bfr[ni] = *(const bf16x8*)&Bl[(wc * 64 + ni * 16 + arow) * 32 + kg];
#pragma unroll
    for (int mi = 0; mi < 4; ++mi)
#pragma unroll
      for (int ni = 0; ni < 4; ++ni)
        acc[mi][ni] = __builtin_amdgcn_mfma_f32_16x16x32_bf16(af[mi], bfr[ni], acc[mi][ni], 0, 0, 0);
  }

#pragma unroll
  for (int mi = 0; mi < 4; ++mi) {
#pragma unroll
    for (int r = 0; r < 4; ++r) {
      const int lrow = wr * 64 + mi * 16 + (lane >> 4) * 4 + r;
      const int grow = m0 + lrow;
      if (EPI == 0) {
#pragma unroll
        for (int ni = 0; ni < 4; ++ni) {
          const int gcol = n0 + wc * 64 + ni * 16 + (lane & 15);
          C[(size_t)grow * ldc + gcol] = acc[mi][ni][r];
        }
      } else {
        const int ch = chs[lrow];
        const float d0 = d0s[lrow], d1 = d1s[lrow];
        const float* kcrow = kc + (size_t)ch * 4096 + colbase;
#pragma unroll
        for (int ni = 0; ni < 4; ++ni) {
          const int gcol = n0 + wc * 64 + ni * 16 + (lane & 15);
          float v = acc[mi][ni][r] + kcrow[gcol]
                  + d0 * kd[colbase + gcol] + d1 * kd[4096 + colbase + gcol]
                  + bias[biasoff + gcol];
          if (EPI == 2) {
            const float hh = tanhf(v);
            const float z = zbuf[(size_t)grow * 1024 + gcol];
            const float htm = states[(size_t)grow * 1026 + gcol];
            const float h = z * htm + (1.f - z) * hh;
            out2[(size_t)grow * NS_STRIDE + gcol] = h;
            hb2[(size_t)grow * 1024 + gcol] = f2bf(h);
          } else {
            out2[(size_t)grow * OUT_STRIDE + gcol] = tanhf(v);
          }
        }
      }
    }
  }
}

// ---------- epi1: gates from zr ----------
__global__ __launch_bounds__(256)
void epi1_kernel(const float* __restrict__ zr,
                 const int* __restrict__ chv,
                 const float* __restrict__ states,
                 const float* __restrict__ kc,
                 const float* __restrict__ kd,
                 const float* __restrict__ bias_z,
                 const float* __restrict__ bias,
                 float* __restrict__ zbuf,
                 unsigned short* __restrict__ rh) {
  const int idx = blockIdx.x * 256 + threadIdx.x;  // 1M
  const int b = idx >> 8, u = (idx & 255) * 4;
  const int ch = chv[b];
  const float* srow = states + (size_t)b * 1026;
  const float d0 = srow[1024], d1 = srow[1025];
  f32x4 az = *(const f32x4*)&zr[(size_t)b * 2048 + u];
  f32x4 ar = *(const f32x4*)&zr[(size_t)b * 2048 + 1024 + u];
  const float* kcrow = kc + (size_t)ch * 4096;
  f32x4 kz = *(const f32x4*)&kcrow[u];
  f32x4 kr = *(const f32x4*)&kcrow[1024 + u];
  f32x4 kd0z = *(const f32x4*)&kd[u];
  f32x4 kd1z = *(const f32x4*)&kd[4096 + u];
  f32x4 kd0r = *(const f32x4*)&kd[1024 + u];
  f32x4 kd1r = *(const f32x4*)&kd[4096 + 1024 + u];
  f32x4 bz = *(const f32x4*)&bias_z[u];
  f32x4 br = *(const f32x4*)&bias[u];
  f32x2 h01 = *(const f32x2*)&srow[u];
  f32x2 h23 = *(const f32x2*)&srow[u + 2];
  float hv[4] = {h01[0], h01[1], h23[0], h23[1]};
  f32x4 zout;
  u16x4 rhv;
#pragma unroll
  for (int i = 0; i < 4; ++i) {
    const float zi = sigmoidf(az[i] + kz[i] + d0 * kd0z[i] + d1 * kd1z[i] + bz[i]);
    const float ri = sigmoidf(ar[i] + kr[i] + d0 * kd0r[i] + d1 * kd1r[i] + br[i]);
    zout[i] = zi;
    rhv[i] = f2bf(ri * hv[i]);
  }
  *(f32x4*)&zbuf[(size_t)b * 1024 + u] = zout;
  *(u16x4*)&rh[(size_t)b * 1024 + u] = rhv;
}

// ---------- GMM head: gmm = o @ Wg + bg ; softmax ; preds ----------
__global__ __launch_bounds__(512)
void gmm_kernel(const float* __restrict__ obuf,  // d_out (o rows, stride 1086)
                const float* __restrict__ Wg,    // [1024][60]
                const float* __restrict__ bg,    // [60]
                float* __restrict__ outp,
                float* __restrict__ ns) {
  __shared__ float Wl[128 * 60 + 16];
  __shared__ float ol[8 * 1024];
  const int tid = threadIdx.x;
  const int lane = tid & 63;
  const int wave = tid >> 6;  // 0..7
  const int row0 = blockIdx.x * 8;

  for (int i = tid; i < 4096; i += 512) {
    const int rr = i >> 9, c2 = (i & 511) * 2;
    *(f32x2*)&ol[rr * 1024 + c2] = *(const f32x2*)&obuf[(size_t)(row0 + rr) * OUT_STRIDE + c2];
  }

  float g = 0.f;
  for (int kc0 = 0; kc0 < 1024; kc0 += 128) {
    __syncthreads();
    for (int i = tid; i < 1920; i += 512)
      *(f32x4*)&Wl[i * 4] = *(const f32x4*)&Wg[kc0 * 60 + i * 4];
    __syncthreads();
    const float* orow = &ol[wave * 1024 + kc0];
#pragma unroll 8
    for (int k = 0; k < 128; ++k)
      g = fmaf(orow[k], Wl[k * 60 + lane], g);
  }
  if (lane < 60) g += bg[lane];

  float e = 0.f;
  if (lane < 20) e = fminf(fmaxf(expf(g), 1e-10f), 1e10f);
  float s = e;
#pragma unroll
  for (int m = 1; m < 32; m <<= 1) s += __shfl_xor(s, m, 64);
  const float pi = (lane < 20) ? e / s : 0.f;
  const int src1 = (lane < 20) ? lane + 20 : lane;
  const int src2 = (lane < 20) ? lane + 40 : lane;
  const float mux = __shfl(g, src1, 64);
  const float muy = __shfl(g, src2, 64);
  float px = pi * mux, py = pi * muy;
#pragma unroll
  for (int m = 1; m < 32; m <<= 1) { px += __shfl_xor(px, m, 64); py += __shfl_xor(py, m, 64); }

  const int row = row0 + wave;
  float* orow = outp + (size_t)row * OUT_STRIDE;
  if (lane < 20) orow[1024 + lane] = pi;
  else if (lane < 60) orow[1024 + lane] = g;
  if (lane == 0) {
    orow[1084] = px;
    orow[1085] = py;
    ns[(size_t)row * NS_STRIDE + 1024] = px;
    ns[(size_t)row * NS_STRIDE + 1025] = py;
  }
}

extern "C" void kernel_launch(void* const* d_in, const int* in_sizes, int n_in,
                              void* d_out, int out_size, void* d_ws, size_t ws_size,
                              hipStream_t stream) {
  const int*   chv     = (const int*)d_in[0];
  const float* states  = (const float*)d_in[1];
  const float* bias_z  = (const float*)d_in[2];
  const float* R       = (const float*)d_in[3];
  const float* kc      = (const float*)d_in[4];
  const float* bias    = (const float*)d_in[5];
  const float* kd      = (const float*)d_in[6];
  const float* Wg      = (const float*)d_in[7];
  const float* bg      = (const float*)d_in[8];
  float* out = (float*)d_out;

  char* ws = (char*)d_ws;
  unsigned short* RbT = (unsigned short*)ws;                    // 8,388,608 B
  unsigned short* hb  = (unsigned short*)(ws + 8388608);        // 8,388,608 B (reused as rh)
  float*          zr  = (float*)(ws + 16777216);                // 33,554,432 B (reused as hb2)
  float*          zbuf= (float*)(ws + 50331648);                // 16,777,216 B  -> total 64 MB
  unsigned short* rh  = hb;
  unsigned short* hb2 = (unsigned short*)zr;

  transposeR<<<dim3(64, 16), 256, 0, stream>>>(R, RbT);
  convertH<<<4096, 256, 0, stream>>>(states, hb);

  // GEMM1: zr = h @ R[:, :2048]
  gemm_k<0><<<dim3(16, 32), 256, 0, stream>>>(hb, RbT, zr, 2048,
      nullptr, nullptr, nullptr, 0, nullptr, nullptr, 0, nullptr, nullptr, nullptr);

  epi1_kernel<<<4096, 256, 0, stream>>>(zr, chv, states, kc, kd, bias_z, bias, zbuf, rh);

  // GEMM2 (+epilogue): h -> new_state + hb2
  gemm_k<2><<<dim3(8, 32), 256, 0, stream>>>(rh, RbT + (size_t)2048 * 1024, nullptr, 0,
      chv, states, kc, 2048, kd, bias, 1024, zbuf, out + NS_BASE, hb2);

  // GEMM3 (+epilogue): o -> out
  gemm_k<3><<<dim3(8, 32), 256, 0, stream>>>(hb2, RbT + (size_t)3072 * 1024, nullptr, 0,
      chv, states, kc, 3072, kd, bias, 2048, nullptr, out, nullptr);

  gmm_kernel<<<512, 512, 0, stream>>>(out, Wg, bg, out, out + NS_BASE);
}

// Round 3
// 339.803 us; speedup vs baseline: 1.0120x; 1.0120x over previous
//
#include <hip/hip_runtime.h>

typedef __attribute__((ext_vector_type(8))) short     bf16x8;
typedef __attribute__((ext_vector_type(4))) float     f32x4;
typedef __attribute__((ext_vector_type(2))) float     f32x2;
typedef __attribute__((ext_vector_type(4))) unsigned short u16x4;

#define OUT_STRIDE 1086  // o(1024) + pi(20) + mux(20) + muy(20) + xp + yp
#define NS_STRIDE 1026
#define NS_BASE (4096*1086)

__device__ __forceinline__ unsigned short f2bf(float x) {
  unsigned int u = __float_as_uint(x);
  unsigned int r = (u + 0x7FFFu + ((u >> 16) & 1u)) >> 16;
  return (unsigned short)r;
}
__device__ __forceinline__ float bf2f(unsigned short u) {
  union { unsigned int i; float f; } v; v.i = ((unsigned int)u) << 16; return v.f;
}
__device__ __forceinline__ float sigmoidf(float x) { return 1.f / (1.f + expf(-x)); }

__device__ __forceinline__ void gld_lds16(const void* g, void* l) {
  __builtin_amdgcn_global_load_lds((const __attribute__((address_space(1))) void*)g,
                                   (__attribute__((address_space(3))) void*)l, 16, 0, 0);
}

// XCD-chunked decode for 32m x 16n grids (512 blocks): XCD x gets an 8x8 tile chunk
// whose L2 footprint (2MB A-panels + 1-2MB B-panels) fits the 4MB per-XCD L2.
__device__ __forceinline__ void decode_block(int bid, int& m0, int& n0) {
  const int swz = (bid & 7) * 64 + (bid >> 3);   // bijective: 512 % 8 == 0
  const int chunk = swz >> 6, l = swz & 63;
  m0 = ((chunk & 3) * 8 + (l >> 3)) * 128;       // mb in [0,32)
  n0 = ((chunk >> 2) * 8 + (l & 7)) * 64;        // nb in [0,16)
}

// ---------- transpose-convert R (1024 x 4096 f32) -> RbT (4096 x 1024 bf16) ----------
__global__ __launch_bounds__(256)
void transposeR(const float* __restrict__ R, unsigned short* __restrict__ Bt) {
  __shared__ float t[64][65];
  const int tx = threadIdx.x & 63, ty = threadIdx.x >> 6;
  const int j0 = blockIdx.x * 64, k0 = blockIdx.y * 64;
#pragma unroll
  for (int i = 0; i < 64; i += 4)
    t[ty + i][tx] = R[(size_t)(k0 + ty + i) * 4096 + j0 + tx];
  __syncthreads();
#pragma unroll
  for (int i = 0; i < 64; i += 4) {
    const int j = ty + i;
    Bt[(size_t)(j0 + j) * 1024 + k0 + tx] = f2bf(t[tx][j]);
  }
}

// ---------- convert h_tm1 (states[:, :1024]) -> bf16 ----------
__global__ __launch_bounds__(256)
void convertH(const float* __restrict__ states, unsigned short* __restrict__ hb) {
  const int idx = blockIdx.x * 256 + threadIdx.x;
  const int b = idx >> 8, u = (idx & 255) * 4;
  const float* sp = states + (size_t)b * 1026 + u;
  f32x2 v0 = *(const f32x2*)sp, v1 = *(const f32x2*)(sp + 2);
  u16x4 w;
  w[0] = f2bf(v0[0]); w[1] = f2bf(v0[1]); w[2] = f2bf(v1[0]); w[3] = f2bf(v1[1]);
  *(u16x4*)&hb[(size_t)b * 1024 + u] = w;
}

// ---------- GEMM1 fused: zr = h@R[:, :2048] (+pre+bias) -> z (f32), rh (bf16) ----------
// tile 128m x (64 z-cols + 64 r-cols), K=1024, double-buffered LDS, 1 barrier/K-step.
__global__ __launch_bounds__(256)
void gemm_zr(const unsigned short* __restrict__ A,   // hb [4096][1024]
             const unsigned short* __restrict__ Bt,  // RbT [4096][1024]
             const int* __restrict__ chv,
             const float* __restrict__ states,
             const float* __restrict__ kc,
             const float* __restrict__ kd,
             const float* __restrict__ bias_z,
             const float* __restrict__ bias,
             float* __restrict__ zbuf,
             unsigned short* __restrict__ rh) {
  __shared__ unsigned short Al[2][128 * 32];
  __shared__ unsigned short Bzl[2][64 * 32];
  __shared__ unsigned short Brl[2][64 * 32];
  __shared__ int   chs[128];
  __shared__ float d0s[128], d1s[128];

  const int tid = threadIdx.x, lane = tid & 63, wave = tid >> 6;
  int m0, n0;
  decode_block(blockIdx.x, m0, n0);

  if (tid < 128) {
    const int r = m0 + tid;
    chs[tid] = chv[r];
    d0s[tid] = states[(size_t)r * 1026 + 1024];
    d1s[tid] = states[(size_t)r * 1026 + 1025];
  }

  const unsigned short* Ag  = A  + (size_t)m0 * 1024;
  const unsigned short* Bzg = Bt + (size_t)n0 * 1024;
  const unsigned short* Brg = Bt + (size_t)(1024 + n0) * 1024;

  const int c1 = tid + 256;
  const int ar0 = tid >> 2, ak0 = (tid & 3) * 8;   // A rows 0..63
  const int ar1 = c1 >> 2,  ak1 = (c1 & 3) * 8;    // A rows 64..127
  // B: 256 chunks, row tid>>2 in [0,64), same ak0

  f32x4 accz[2][4] = {}, accr[2][4] = {};

#define STAGE_ZR(b, kk)                                                        \
  gld_lds16(Ag  + (size_t)ar0 * 1024 + (kk) + ak0, &Al[b][tid * 8]);           \
  gld_lds16(Ag  + (size_t)ar1 * 1024 + (kk) + ak1, &Al[b][c1 * 8]);            \
  gld_lds16(Bzg + (size_t)ar0 * 1024 + (kk) + ak0, &Bzl[b][tid * 8]);          \
  gld_lds16(Brg + (size_t)ar0 * 1024 + (kk) + ak0, &Brl[b][tid * 8]);

  STAGE_ZR(0, 0);
  __syncthreads();

  const int arow = lane & 15, kg = (lane >> 4) * 8;
  for (int t = 0; t < 32; ++t) {
    const int cb = t & 1;
    if (t < 31) { STAGE_ZR(cb ^ 1, (t + 1) * 32); }
    bf16x8 af[2], bzf[4], brf[4];
#pragma unroll
    for (int mi = 0; mi < 2; ++mi)
      af[mi] = *(const bf16x8*)&Al[cb][(wave * 32 + mi * 16 + arow) * 32 + kg];
#pragma unroll
    for (int ni = 0; ni < 4; ++ni) {
      bzf[ni] = *(const bf16x8*)&Bzl[cb][(ni * 16 + arow) * 32 + kg];
      brf[ni] = *(const bf16x8*)&Brl[cb][(ni * 16 + arow) * 32 + kg];
    }
#pragma unroll
    for (int mi = 0; mi < 2; ++mi)
#pragma unroll
      for (int ni = 0; ni < 4; ++ni) {
        accz[mi][ni] = __builtin_amdgcn_mfma_f32_16x16x32_bf16(af[mi], bzf[ni], accz[mi][ni], 0, 0, 0);
        accr[mi][ni] = __builtin_amdgcn_mfma_f32_16x16x32_bf16(af[mi], brf[ni], accr[mi][ni], 0, 0, 0);
      }
    if (t < 31) __syncthreads();
  }
#undef STAGE_ZR

#pragma unroll
  for (int mi = 0; mi < 2; ++mi) {
#pragma unroll
    for (int r = 0; r < 4; ++r) {
      const int lrow = wave * 32 + mi * 16 + (lane >> 4) * 4 + r;
      const int grow = m0 + lrow;
      const int ch = chs[lrow];
      const float d0 = d0s[lrow], d1 = d1s[lrow];
      const float* kcrow = kc + (size_t)ch * 4096;
#pragma unroll
      for (int ni = 0; ni < 4; ++ni) {
        const int jc = n0 + ni * 16 + (lane & 15);
        const float vz = accz[mi][ni][r] + kcrow[jc]
                       + d0 * kd[jc] + d1 * kd[4096 + jc] + bias_z[jc];
        const float vr = accr[mi][ni][r] + kcrow[1024 + jc]
                       + d0 * kd[1024 + jc] + d1 * kd[4096 + 1024 + jc] + bias[jc];
        const float z = sigmoidf(vz);
        const float rr = sigmoidf(vr);
        zbuf[(size_t)grow * 1024 + jc] = z;
        rh[(size_t)grow * 1024 + jc] = f2bf(rr * bf2f(A[(size_t)grow * 1024 + jc]));
      }
    }
  }
}

// ---------- GEMM 2/3: C[4096, 1024] = A @ Bt^T, tile 128x64, dbuf ----------
// EPI 2: hh -> h epilogue (new_state + h bf16).  EPI 3: o epilogue.
template<int EPI>
__global__ __launch_bounds__(256)
void gemm_k(const unsigned short* __restrict__ A,
            const unsigned short* __restrict__ Bt,   // pre-offset panel base
            const int* __restrict__ chv,
            const float* __restrict__ states,
            const float* __restrict__ kc, int colbase,
            const float* __restrict__ kd,
            const float* __restrict__ bias, int biasoff,
            const float* __restrict__ zbuf,
            float* __restrict__ out2,
            unsigned short* __restrict__ hb2) {
  __shared__ unsigned short Al[2][128 * 32];
  __shared__ unsigned short Bl[2][64 * 32];
  __shared__ int   chs[128];
  __shared__ float d0s[128], d1s[128];

  const int tid = threadIdx.x, lane = tid & 63, wave = tid >> 6;
  int m0, n0;
  decode_block(blockIdx.x, m0, n0);

  if (tid < 128) {
    const int r = m0 + tid;
    chs[tid] = chv[r];
    d0s[tid] = states[(size_t)r * 1026 + 1024];
    d1s[tid] = states[(size_t)r * 1026 + 1025];
  }

  const unsigned short* Ag = A  + (size_t)m0 * 1024;
  const unsigned short* Bg = Bt + (size_t)n0 * 1024;

  const int c1 = tid + 256;
  const int ar0 = tid >> 2, ak0 = (tid & 3) * 8;
  const int ar1 = c1 >> 2,  ak1 = (c1 & 3) * 8;

  f32x4 acc[2][4] = {};

#define STAGE_K(b, kk)                                                         \
  gld_lds16(Ag + (size_t)ar0 * 1024 + (kk) + ak0, &Al[b][tid * 8]);            \
  gld_lds16(Ag + (size_t)ar1 * 1024 + (kk) + ak1, &Al[b][c1 * 8]);             \
  gld_lds16(Bg + (size_t)ar0 * 1024 + (kk) + ak0, &Bl[b][tid * 8]);

  STAGE_K(0, 0);
  __syncthreads();

  const int arow = lane & 15, kg = (lane >> 4) * 8;
  for (int t = 0; t < 32; ++t) {
    const int cb = t & 1;
    if (t < 31) { STAGE_K(cb ^ 1, (t + 1) * 32); }
    bf16x8 af[2], bf[4];
#pragma unroll
    for (int mi = 0; mi < 2; ++mi)
      af[mi] = *(const bf16x8*)&Al[cb][(wave * 32 + mi * 16 + arow) * 32 + kg];
#pragma unroll
    for (int ni = 0; ni < 4; ++ni)
      bf[ni] = *(const bf16x8*)&Bl[cb][(ni * 16 + arow) * 32 + kg];
#pragma unroll
    for (int mi = 0; mi < 2; ++mi)
#pragma unroll
      for (int ni = 0; ni < 4; ++ni)
        acc[mi][ni] = __builtin_amdgcn_mfma_f32_16x16x32_bf16(af[mi], bf[ni], acc[mi][ni], 0, 0, 0);
    if (t < 31) __syncthreads();
  }
#undef STAGE_K

#pragma unroll
  for (int mi = 0; mi < 2; ++mi) {
#pragma unroll
    for (int r = 0; r < 4; ++r) {
      const int lrow = wave * 32 + mi * 16 + (lane >> 4) * 4 + r;
      const int grow = m0 + lrow;
      const int ch = chs[lrow];
      const float d0 = d0s[lrow], d1 = d1s[lrow];
      const float* kcrow = kc + (size_t)ch * 4096 + colbase;
#pragma unroll
      for (int ni = 0; ni < 4; ++ni) {
        const int gcol = n0 + ni * 16 + (lane & 15);
        float v = acc[mi][ni][r] + kcrow[gcol]
                + d0 * kd[colbase + gcol] + d1 * kd[4096 + colbase + gcol]
                + bias[biasoff + gcol];
        if (EPI == 2) {
          const float hh = tanhf(v);
          const float z = zbuf[(size_t)grow * 1024 + gcol];
          const float htm = states[(size_t)grow * 1026 + gcol];
          const float h = z * htm + (1.f - z) * hh;
          out2[(size_t)grow * NS_STRIDE + gcol] = h;
          hb2[(size_t)grow * 1024 + gcol] = f2bf(h);
        } else {
          out2[(size_t)grow * OUT_STRIDE + gcol] = tanhf(v);
        }
      }
    }
  }
}

// ---------- GMM head: gmm = o @ Wg + bg ; softmax ; preds ----------
__global__ __launch_bounds__(512)
void gmm_kernel(const float* __restrict__ obuf,
                const float* __restrict__ Wg,
                const float* __restrict__ bg,
                float* __restrict__ outp,
                float* __restrict__ ns) {
  __shared__ float Wl[128 * 60 + 16];
  __shared__ float ol[8 * 1024];
  const int tid = threadIdx.x;
  const int lane = tid & 63;
  const int wave = tid >> 6;
  const int row0 = blockIdx.x * 8;

  for (int i = tid; i < 4096; i += 512) {
    const int rr = i >> 9, c2 = (i & 511) * 2;
    *(f32x2*)&ol[rr * 1024 + c2] = *(const f32x2*)&obuf[(size_t)(row0 + rr) * OUT_STRIDE + c2];
  }

  float g = 0.f;
  for (int kc0 = 0; kc0 < 1024; kc0 += 128) {
    __syncthreads();
    for (int i = tid; i < 1920; i += 512)
      *(f32x4*)&Wl[i * 4] = *(const f32x4*)&Wg[kc0 * 60 + i * 4];
    __syncthreads();
    const float* orow = &ol[wave * 1024 + kc0];
#pragma unroll 8
    for (int k = 0; k < 128; ++k)
      g = fmaf(orow[k], Wl[k * 60 + lane], g);
  }
  if (lane < 60) g += bg[lane];

  float e = 0.f;
  if (lane < 20) e = fminf(fmaxf(expf(g), 1e-10f), 1e10f);
  float s = e;
#pragma unroll
  for (int m = 1; m < 32; m <<= 1) s += __shfl_xor(s, m, 64);
  const float pi = (lane < 20) ? e / s : 0.f;
  const int src1 = (lane < 20) ? lane + 20 : lane;
  const int src2 = (lane < 20) ? lane + 40 : lane;
  const float mux = __shfl(g, src1, 64);
  const float muy = __shfl(g, src2, 64);
  float px = pi * mux, py = pi * muy;
#pragma unroll
  for (int m = 1; m < 32; m <<= 1) { px += __shfl_xor(px, m, 64); py += __shfl_xor(py, m, 64); }

  const int row = row0 + wave;
  float* orow = outp + (size_t)row * OUT_STRIDE;
  if (lane < 20) orow[1024 + lane] = pi;
  else if (lane < 60) orow[1024 + lane] = g;
  if (lane == 0) {
    orow[1084] = px;
    orow[1085] = py;
    ns[(size_t)row * NS_STRIDE + 1024] = px;
    ns[(size_t)row * NS_STRIDE + 1025] = py;
  }
}

extern "C" void kernel_launch(void* const* d_in, const int* in_sizes, int n_in,
                              void* d_out, int out_size, void* d_ws, size_t ws_size,
                              hipStream_t stream) {
  const int*   chv    = (const int*)d_in[0];
  const float* states = (const float*)d_in[1];
  const float* bias_z = (const float*)d_in[2];
  const float* R      = (const float*)d_in[3];
  const float* kc     = (const float*)d_in[4];
  const float* bias   = (const float*)d_in[5];
  const float* kd     = (const float*)d_in[6];
  const float* Wg     = (const float*)d_in[7];
  const float* bg     = (const float*)d_in[8];
  float* out = (float*)d_out;

  char* ws = (char*)d_ws;
  unsigned short* RbT  = (unsigned short*)ws;                   // 8 MB
  unsigned short* hb   = (unsigned short*)(ws + 8388608);       // 8 MB
  unsigned short* rh   = (unsigned short*)(ws + 16777216);      // 8 MB
  unsigned short* hb2  = (unsigned short*)(ws + 25165824);      // 8 MB
  float*          zbuf = (float*)(ws + 33554432);               // 16 MB -> 48 MB total

  transposeR<<<dim3(64, 16), 256, 0, stream>>>(R, RbT);
  convertH<<<4096, 256, 0, stream>>>(states, hb);

  // GEMM1 fused: z (f32) + rh (bf16)
  gemm_zr<<<512, 256, 0, stream>>>(hb, RbT, chv, states, kc, kd, bias_z, bias, zbuf, rh);

  // GEMM2 (+epilogue): h -> new_state + hb2
  gemm_k<2><<<512, 256, 0, stream>>>(rh, RbT + (size_t)2048 * 1024,
      chv, states, kc, 2048, kd, bias, 1024, zbuf, out + NS_BASE, hb2);

  // GEMM3 (+epilogue): o -> out
  gemm_k<3><<<512, 256, 0, stream>>>(hb2, RbT + (size_t)3072 * 1024,
      chv, states, kc, 3072, kd, bias, 2048, nullptr, out, nullptr);

  gmm_kernel<<<512, 512, 0, stream>>>(out, Wg, bg, out, out + NS_BASE);
}

// Round 4
// 328.689 us; speedup vs baseline: 1.0462x; 1.0338x over previous
//
#include <hip/hip_runtime.h>

typedef __attribute__((ext_vector_type(8))) short     bf16x8;
typedef __attribute__((ext_vector_type(4))) float     f32x4;
typedef __attribute__((ext_vector_type(2))) float     f32x2;
typedef __attribute__((ext_vector_type(4))) unsigned short u16x4;

#define OUT_STRIDE 1086
#define NS_STRIDE 1026
#define NS_BASE (4096*1086)

__device__ __forceinline__ unsigned short f2bf(float x) {
  unsigned int u = __float_as_uint(x);
  unsigned int r = (u + 0x7FFFu + ((u >> 16) & 1u)) >> 16;
  return (unsigned short)r;
}
__device__ __forceinline__ float bf2f(unsigned short u) {
  union { unsigned int i; float f; } v; v.i = ((unsigned int)u) << 16; return v.f;
}
__device__ __forceinline__ float sigmoidf(float x) { return 1.f / (1.f + expf(-x)); }

__device__ __forceinline__ void gld_lds16(const void* g, void* l) {
  __builtin_amdgcn_global_load_lds((const __attribute__((address_space(1))) void*)g,
                                   (__attribute__((address_space(3))) void*)l, 16, 0, 0);
}

// XCD-chunked decode for 32m x 16n grids (512 blocks).
__device__ __forceinline__ void decode_block(int bid, int& m0, int& n0) {
  const int swz = (bid & 7) * 64 + (bid >> 3);   // bijective: 512 % 8 == 0
  const int chunk = swz >> 6, l = swz & 63;
  m0 = ((chunk & 3) * 8 + (l >> 3)) * 128;
  n0 = ((chunk >> 2) * 8 + (l & 7)) * 64;
}

// ---------- transpose-convert R (1024 x 4096 f32) -> RbT (4096 x 1024 bf16) ----------
__global__ __launch_bounds__(256)
void transposeR(const float* __restrict__ R, unsigned short* __restrict__ Bt) {
  __shared__ float t[64][65];
  const int tx = threadIdx.x & 63, ty = threadIdx.x >> 6;
  const int j0 = blockIdx.x * 64, k0 = blockIdx.y * 64;
#pragma unroll
  for (int i = 0; i < 64; i += 4)
    t[ty + i][tx] = R[(size_t)(k0 + ty + i) * 4096 + j0 + tx];
  __syncthreads();
#pragma unroll
  for (int i = 0; i < 64; i += 4) {
    const int j = ty + i;
    Bt[(size_t)(j0 + j) * 1024 + k0 + tx] = f2bf(t[tx][j]);
  }
}

// ---------- convert h_tm1 -> bf16 ----------
__global__ __launch_bounds__(256)
void convertH(const float* __restrict__ states, unsigned short* __restrict__ hb) {
  const int idx = blockIdx.x * 256 + threadIdx.x;
  const int b = idx >> 8, u = (idx & 255) * 4;
  const float* sp = states + (size_t)b * 1026 + u;
  f32x2 v0 = *(const f32x2*)sp, v1 = *(const f32x2*)(sp + 2);
  u16x4 w;
  w[0] = f2bf(v0[0]); w[1] = f2bf(v0[1]); w[2] = f2bf(v1[0]); w[3] = f2bf(v1[1]);
  *(u16x4*)&hb[(size_t)b * 1024 + u] = w;
}

// ---------- GEMM1 fused: z (f32) + rh (bf16). 4-buffer depth-2 pipeline ----------
__global__ __launch_bounds__(256)
void gemm_zr(const unsigned short* __restrict__ A,
             const unsigned short* __restrict__ Bt,
             const int* __restrict__ chv,
             const float* __restrict__ states,
             const float* __restrict__ kc,
             const float* __restrict__ kd,
             const float* __restrict__ bias_z,
             const float* __restrict__ bias,
             float* __restrict__ zbuf,
             unsigned short* __restrict__ rh) {
  __shared__ unsigned short Al[4][128 * 32];
  __shared__ unsigned short Bzl[4][64 * 32];
  __shared__ unsigned short Brl[4][64 * 32];
  __shared__ int   chs[128];
  __shared__ float d0s[128], d1s[128];

  const int tid = threadIdx.x, lane = tid & 63, wave = tid >> 6;
  int m0, n0;
  decode_block(blockIdx.x, m0, n0);

  if (tid < 128) {
    const int r = m0 + tid;
    chs[tid] = chv[r];
    d0s[tid] = states[(size_t)r * 1026 + 1024];
    d1s[tid] = states[(size_t)r * 1026 + 1025];
  }

  const unsigned short* Ag  = A  + (size_t)m0 * 1024;
  const unsigned short* Bzg = Bt + (size_t)n0 * 1024;
  const unsigned short* Brg = Bt + (size_t)(1024 + n0) * 1024;

  const int c1 = tid + 256;
  const int ar0 = tid >> 2, ak0 = (tid & 3) * 8;
  const int ar1 = c1 >> 2,  ak1 = (c1 & 3) * 8;

  f32x4 accz[2][4] = {}, accr[2][4] = {};
  const int arow = lane & 15, kg = (lane >> 4) * 8;

#define STAGE_ZR(b, kk)                                                        \
  gld_lds16(Ag  + (size_t)ar0 * 1024 + (kk) + ak0, &Al[b][tid * 8]);           \
  gld_lds16(Ag  + (size_t)ar1 * 1024 + (kk) + ak1, &Al[b][c1 * 8]);            \
  gld_lds16(Bzg + (size_t)ar0 * 1024 + (kk) + ak0, &Bzl[b][tid * 8]);          \
  gld_lds16(Brg + (size_t)ar0 * 1024 + (kk) + ak0, &Brl[b][tid * 8]);

  auto compute = [&](int cb) {
    bf16x8 af[2], bzf[4], brf[4];
#pragma unroll
    for (int mi = 0; mi < 2; ++mi)
      af[mi] = *(const bf16x8*)&Al[cb][(wave * 32 + mi * 16 + arow) * 32 + kg];
#pragma unroll
    for (int ni = 0; ni < 4; ++ni) {
      bzf[ni] = *(const bf16x8*)&Bzl[cb][(ni * 16 + arow) * 32 + kg];
      brf[ni] = *(const bf16x8*)&Brl[cb][(ni * 16 + arow) * 32 + kg];
    }
    __builtin_amdgcn_s_setprio(1);
#pragma unroll
    for (int mi = 0; mi < 2; ++mi)
#pragma unroll
      for (int ni = 0; ni < 4; ++ni) {
        accz[mi][ni] = __builtin_amdgcn_mfma_f32_16x16x32_bf16(af[mi], bzf[ni], accz[mi][ni], 0, 0, 0);
        accr[mi][ni] = __builtin_amdgcn_mfma_f32_16x16x32_bf16(af[mi], brf[ni], accr[mi][ni], 0, 0, 0);
      }
    __builtin_amdgcn_s_setprio(0);
  };

  STAGE_ZR(0, 0);
  STAGE_ZR(1, 32);
  for (int t = 0; t < 30; ++t) {
    const int nx = (t + 2) & 3;
    STAGE_ZR(nx, (t + 2) * 32);
    asm volatile("s_waitcnt vmcnt(8)" ::: "memory");   // keep 2 stages (8 loads) in flight
    __builtin_amdgcn_s_barrier();
    asm volatile("" ::: "memory");
    compute(t & 3);
  }
  asm volatile("s_waitcnt vmcnt(4)" ::: "memory");
  __builtin_amdgcn_s_barrier();
  asm volatile("" ::: "memory");
  compute(2);
  asm volatile("s_waitcnt vmcnt(0)" ::: "memory");
  __builtin_amdgcn_s_barrier();
  asm volatile("" ::: "memory");
  compute(3);
#undef STAGE_ZR

#pragma unroll
  for (int mi = 0; mi < 2; ++mi) {
#pragma unroll
    for (int r = 0; r < 4; ++r) {
      const int lrow = wave * 32 + mi * 16 + (lane >> 4) * 4 + r;
      const int grow = m0 + lrow;
      const int ch = chs[lrow];
      const float d0 = d0s[lrow], d1 = d1s[lrow];
      const float* kcrow = kc + (size_t)ch * 4096;
#pragma unroll
      for (int ni = 0; ni < 4; ++ni) {
        const int jc = n0 + ni * 16 + (lane & 15);
        const float vz = accz[mi][ni][r] + kcrow[jc]
                       + d0 * kd[jc] + d1 * kd[4096 + jc] + bias_z[jc];
        const float vr = accr[mi][ni][r] + kcrow[1024 + jc]
                       + d0 * kd[1024 + jc] + d1 * kd[4096 + 1024 + jc] + bias[jc];
        const float z = sigmoidf(vz);
        const float rr = sigmoidf(vr);
        zbuf[(size_t)grow * 1024 + jc] = z;
        rh[(size_t)grow * 1024 + jc] = f2bf(rr * bf2f(A[(size_t)grow * 1024 + jc]));
      }
    }
  }
}

// ---------- GEMM 2/3: 128x64 tile, 4-buffer depth-2 pipeline ----------
template<int EPI>
__global__ __launch_bounds__(256)
void gemm_k(const unsigned short* __restrict__ A,
            const unsigned short* __restrict__ Bt,
            const int* __restrict__ chv,
            const float* __restrict__ states,
            const float* __restrict__ kc, int colbase,
            const float* __restrict__ kd,
            const float* __restrict__ bias, int biasoff,
            const float* __restrict__ zbuf,
            float* __restrict__ out2,
            unsigned short* __restrict__ hb2) {
  __shared__ unsigned short Al[4][128 * 32];
  __shared__ unsigned short Bl[4][64 * 32];
  __shared__ int   chs[128];
  __shared__ float d0s[128], d1s[128];

  const int tid = threadIdx.x, lane = tid & 63, wave = tid >> 6;
  int m0, n0;
  decode_block(blockIdx.x, m0, n0);

  if (tid < 128) {
    const int r = m0 + tid;
    chs[tid] = chv[r];
    d0s[tid] = states[(size_t)r * 1026 + 1024];
    d1s[tid] = states[(size_t)r * 1026 + 1025];
  }

  const unsigned short* Ag = A  + (size_t)m0 * 1024;
  const unsigned short* Bg = Bt + (size_t)n0 * 1024;

  const int c1 = tid + 256;
  const int ar0 = tid >> 2, ak0 = (tid & 3) * 8;
  const int ar1 = c1 >> 2,  ak1 = (c1 & 3) * 8;

  f32x4 acc[2][4] = {};
  const int arow = lane & 15, kg = (lane >> 4) * 8;

#define STAGE_K(b, kk)                                                         \
  gld_lds16(Ag + (size_t)ar0 * 1024 + (kk) + ak0, &Al[b][tid * 8]);            \
  gld_lds16(Ag + (size_t)ar1 * 1024 + (kk) + ak1, &Al[b][c1 * 8]);             \
  gld_lds16(Bg + (size_t)ar0 * 1024 + (kk) + ak0, &Bl[b][tid * 8]);

  auto compute = [&](int cb) {
    bf16x8 af[2], bfr[4];
#pragma unroll
    for (int mi = 0; mi < 2; ++mi)
      af[mi] = *(const bf16x8*)&Al[cb][(wave * 32 + mi * 16 + arow) * 32 + kg];
#pragma unroll
    for (int ni = 0; ni < 4; ++ni)
      bfr[ni] = *(const bf16x8*)&Bl[cb][(ni * 16 + arow) * 32 + kg];
    __builtin_amdgcn_s_setprio(1);
#pragma unroll
    for (int mi = 0; mi < 2; ++mi)
#pragma unroll
      for (int ni = 0; ni < 4; ++ni)
        acc[mi][ni] = __builtin_amdgcn_mfma_f32_16x16x32_bf16(af[mi], bfr[ni], acc[mi][ni], 0, 0, 0);
    __builtin_amdgcn_s_setprio(0);
  };

  STAGE_K(0, 0);
  STAGE_K(1, 32);
  for (int t = 0; t < 30; ++t) {
    const int nx = (t + 2) & 3;
    STAGE_K(nx, (t + 2) * 32);
    asm volatile("s_waitcnt vmcnt(6)" ::: "memory");   // keep 2 stages (6 loads) in flight
    __builtin_amdgcn_s_barrier();
    asm volatile("" ::: "memory");
    compute(t & 3);
  }
  asm volatile("s_waitcnt vmcnt(3)" ::: "memory");
  __builtin_amdgcn_s_barrier();
  asm volatile("" ::: "memory");
  compute(2);
  asm volatile("s_waitcnt vmcnt(0)" ::: "memory");
  __builtin_amdgcn_s_barrier();
  asm volatile("" ::: "memory");
  compute(3);
#undef STAGE_K

#pragma unroll
  for (int mi = 0; mi < 2; ++mi) {
#pragma unroll
    for (int r = 0; r < 4; ++r) {
      const int lrow = wave * 32 + mi * 16 + (lane >> 4) * 4 + r;
      const int grow = m0 + lrow;
      const int ch = chs[lrow];
      const float d0 = d0s[lrow], d1 = d1s[lrow];
      const float* kcrow = kc + (size_t)ch * 4096 + colbase;
#pragma unroll
      for (int ni = 0; ni < 4; ++ni) {
        const int gcol = n0 + ni * 16 + (lane & 15);
        float v = acc[mi][ni][r] + kcrow[gcol]
                + d0 * kd[colbase + gcol] + d1 * kd[4096 + colbase + gcol]
                + bias[biasoff + gcol];
        if (EPI == 2) {
          const float hh = tanhf(v);
          const float z = zbuf[(size_t)grow * 1024 + gcol];
          const float htm = states[(size_t)grow * 1026 + gcol];
          const float h = z * htm + (1.f - z) * hh;
          out2[(size_t)grow * NS_STRIDE + gcol] = h;
          hb2[(size_t)grow * 1024 + gcol] = f2bf(h);
        } else {
          out2[(size_t)grow * OUT_STRIDE + gcol] = tanhf(v);
        }
      }
    }
  }
}

// ---------- GMM head ----------
__global__ __launch_bounds__(512)
void gmm_kernel(const float* __restrict__ obuf,
                const float* __restrict__ Wg,
                const float* __restrict__ bg,
                float* __restrict__ outp,
                float* __restrict__ ns) {
  __shared__ float Wl[128 * 60 + 16];
  __shared__ float ol[8 * 1024];
  const int tid = threadIdx.x;
  const int lane = tid & 63;
  const int wave = tid >> 6;
  const int row0 = blockIdx.x * 8;

  for (int i = tid; i < 4096; i += 512) {
    const int rr = i >> 9, c2 = (i & 511) * 2;
    *(f32x2*)&ol[rr * 1024 + c2] = *(const f32x2*)&obuf[(size_t)(row0 + rr) * OUT_STRIDE + c2];
  }

  float g = 0.f;
  for (int kc0 = 0; kc0 < 1024; kc0 += 128) {
    __syncthreads();
    for (int i = tid; i < 1920; i += 512)
      *(f32x4*)&Wl[i * 4] = *(const f32x4*)&Wg[kc0 * 60 + i * 4];
    __syncthreads();
    const float* orow = &ol[wave * 1024 + kc0];
#pragma unroll 8
    for (int k = 0; k < 128; ++k)
      g = fmaf(orow[k], Wl[k * 60 + lane], g);
  }
  if (lane < 60) g += bg[lane];

  float e = 0.f;
  if (lane < 20) e = fminf(fmaxf(expf(g), 1e-10f), 1e10f);
  float s = e;
#pragma unroll
  for (int m = 1; m < 32; m <<= 1) s += __shfl_xor(s, m, 64);
  const float pi = (lane < 20) ? e / s : 0.f;
  const int src1 = (lane < 20) ? lane + 20 : lane;
  const int src2 = (lane < 20) ? lane + 40 : lane;
  const float mux = __shfl(g, src1, 64);
  const float muy = __shfl(g, src2, 64);
  float px = pi * mux, py = pi * muy;
#pragma unroll
  for (int m = 1; m < 32; m <<= 1) { px += __shfl_xor(px, m, 64); py += __shfl_xor(py, m, 64); }

  const int row = row0 + wave;
  float* orow = outp + (size_t)row * OUT_STRIDE;
  if (lane < 20) orow[1024 + lane] = pi;
  else if (lane < 60) orow[1024 + lane] = g;
  if (lane == 0) {
    orow[1084] = px;
    orow[1085] = py;
    ns[(size_t)row * NS_STRIDE + 1024] = px;
    ns[(size_t)row * NS_STRIDE + 1025] = py;
  }
}

extern "C" void kernel_launch(void* const* d_in, const int* in_sizes, int n_in,
                              void* d_out, int out_size, void* d_ws, size_t ws_size,
                              hipStream_t stream) {
  const int*   chv    = (const int*)d_in[0];
  const float* states = (const float*)d_in[1];
  const float* bias_z = (const float*)d_in[2];
  const float* R      = (const float*)d_in[3];
  const float* kc     = (const float*)d_in[4];
  const float* bias   = (const float*)d_in[5];
  const float* kd     = (const float*)d_in[6];
  const float* Wg     = (const float*)d_in[7];
  const float* bg     = (const float*)d_in[8];
  float* out = (float*)d_out;

  char* ws = (char*)d_ws;
  unsigned short* RbT  = (unsigned short*)ws;                   // 8 MB
  unsigned short* hb   = (unsigned short*)(ws + 8388608);       // 8 MB
  unsigned short* rh   = (unsigned short*)(ws + 16777216);      // 8 MB
  unsigned short* hb2  = (unsigned short*)(ws + 25165824);      // 8 MB
  float*          zbuf = (float*)(ws + 33554432);               // 16 MB

  transposeR<<<dim3(64, 16), 256, 0, stream>>>(R, RbT);
  convertH<<<4096, 256, 0, stream>>>(states, hb);

  gemm_zr<<<512, 256, 0, stream>>>(hb, RbT, chv, states, kc, kd, bias_z, bias, zbuf, rh);

  gemm_k<2><<<512, 256, 0, stream>>>(rh, RbT + (size_t)2048 * 1024,
      chv, states, kc, 2048, kd, bias, 1024, zbuf, out + NS_BASE, hb2);

  gemm_k<3><<<512, 256, 0, stream>>>(hb2, RbT + (size_t)3072 * 1024,
      chv, states, kc, 3072, kd, bias, 2048, nullptr, out, nullptr);

  gmm_kernel<<<512, 512, 0, stream>>>(out, Wg, bg, out, out + NS_BASE);
}